// Round 6
// baseline (323.279 us; speedup 1.0000x reference)
//
#include <hip/hip_runtime.h>
#include <hip/hip_bf16.h>

// TransformerBlock fused kernel for MI355X (gfx950).
// Shapes: B=1024, T=128, D=128, H=4, HD=32, FF=512.
// Inputs: float32-STORED (bf16-valued) — proven by R1-R5 bisection.
// Output: float32 (reference output dtype; harness reads d_out as f32).
// One block per batch element; 512 threads = 8 waves.
// LDS: 4 x [128][136] bf16 buffers (139,264 B), phase-overlaid:
//   bufA: hs(LN1) -> P(softmax scratch) -> reluG
//   bufB: Q       -> attn(concat heads)
//   bufC: K       -> x1 (post-attn residual, bf16 copy for LN2)
//   bufD: Vt (V transposed) -> h2(LN2)
// MFMA 16x16x32 bf16, f32 accumulate.
// A-frag: A[m=lane&15][k=quad*8+j]; B-frag: B[k=quad*8+j][n=lane&15];
// C/D: col=lane&15, row=quad*4+reg  (verified layouts, learn_hip m89/m91).

typedef short bf16x8 __attribute__((ext_vector_type(8)));   // 8 bf16 in 4 VGPRs
typedef float f32x4  __attribute__((ext_vector_type(4)));
typedef unsigned short u16;
typedef unsigned int   u32;

#define TT   128
#define DDIM 128
#define FFD  512
#define PIT  136   // LDS row pitch (bf16): 272 B = 17*16 -> rows 16B-aligned; 4-bank stride -> 2-way (free)

__device__ __forceinline__ u16 f2b(float f) {
    __hip_bfloat16 h = __float2bfloat16(f);   // RNE
    return __builtin_bit_cast(u16, h);
}
__device__ __forceinline__ bf16x8 ldfrag(const u16* p) {  // LDS, 16B-aligned
    return __builtin_bit_cast(bf16x8, *reinterpret_cast<const uint4*>(p));
}
// Load 8 f32 from global, round to bf16 fragment (16B-aligned base).
__device__ __forceinline__ bf16x8 ldfrag_f32(const float* p) {
    float4 a = *reinterpret_cast<const float4*>(p);
    float4 b = *reinterpret_cast<const float4*>(p + 4);
    bf16x8 r;
    r[0] = (short)f2b(a.x); r[1] = (short)f2b(a.y);
    r[2] = (short)f2b(a.z); r[3] = (short)f2b(a.w);
    r[4] = (short)f2b(b.x); r[5] = (short)f2b(b.y);
    r[6] = (short)f2b(b.z); r[7] = (short)f2b(b.w);
    return r;
}
__device__ __forceinline__ f32x4 mfma16(bf16x8 a, bf16x8 b, f32x4 c) {
    return __builtin_amdgcn_mfma_f32_16x16x32_bf16(a, b, c, 0, 0, 0);
}

__global__ __launch_bounds__(512, 2) void tblock_kernel(
    const float* __restrict__ x,
    const float* __restrict__ ln1g, const float* __restrict__ ln1b,
    const float* __restrict__ Wq,   const float* __restrict__ Wk, const float* __restrict__ Wv,
    const float* __restrict__ Wo,   const float* __restrict__ bo,
    const float* __restrict__ ln2g, const float* __restrict__ ln2b,
    const float* __restrict__ W1,   const float* __restrict__ b1,
    const float* __restrict__ W2,   const float* __restrict__ b2,
    float* __restrict__ out)
{
    __shared__ __align__(16) u16 sm[4 * TT * PIT];
    u16* bufA = sm;
    u16* bufB = sm + 1 * TT * PIT;
    u16* bufC = sm + 2 * TT * PIT;
    u16* bufD = sm + 3 * TT * PIT;

    const int b    = blockIdx.x;
    const int tid  = threadIdx.x;
    const int w    = tid >> 6;     // wave id 0..7
    const int l    = tid & 63;
    const int lq   = l & 15;
    const int quad = l >> 4;
    const float* xb = x + (size_t)b * (TT * DDIM);

    // ---------------- P0: LN1(x) -> bufA (bf16) ----------------
    {
        const int row = tid >> 2, part = tid & 3;
        const float* src = xb + row * DDIM + part * 32;
        float v[32];
        float s = 0.f, s2 = 0.f;
        #pragma unroll
        for (int i = 0; i < 8; i++) {
            float4 u = *reinterpret_cast<const float4*>(src + i * 4);
            v[i * 4 + 0] = u.x; v[i * 4 + 1] = u.y;
            v[i * 4 + 2] = u.z; v[i * 4 + 3] = u.w;
            s  += u.x + u.y + u.z + u.w;
            s2 += u.x * u.x + u.y * u.y + u.z * u.z + u.w * u.w;
        }
        s  += __shfl_xor(s, 1);  s2 += __shfl_xor(s2, 1);
        s  += __shfl_xor(s, 2);  s2 += __shfl_xor(s2, 2);
        float mean = s * (1.f / 128.f);
        float var  = fmaxf(s2 * (1.f / 128.f) - mean * mean, 0.f);
        float rstd = rsqrtf(var + 1e-5f);
        u16* dst = bufA + row * PIT + part * 32;
        #pragma unroll
        for (int i = 0; i < 4; i++) {
            u32 o4[4];
            #pragma unroll
            for (int j = 0; j < 4; j++) {
                int c = part * 32 + i * 8 + 2 * j;
                float r0 = (v[i * 8 + 2 * j]     - mean) * rstd * ln1g[c]     + ln1b[c];
                float r1 = (v[i * 8 + 2 * j + 1] - mean) * rstd * ln1g[c + 1] + ln1b[c + 1];
                o4[j] = (u32)f2b(r0) | ((u32)f2b(r1) << 16);
            }
            uint4 pk; pk.x = o4[0]; pk.y = o4[1]; pk.z = o4[2]; pk.w = o4[3];
            *reinterpret_cast<uint4*>(dst + i * 8) = pk;
        }
    }
    __syncthreads();

    // ---------------- P1: Q -> bufB, K -> bufC, Vt -> bufD ----------------
    {
        // Q,K: waves over N (out-cols); weights loaded once per block total.
        bf16x8 bq[4], bk[4];
        #pragma unroll
        for (int ks = 0; ks < 4; ks++) {
            bq[ks] = ldfrag_f32(Wq + (w * 16 + lq) * DDIM + ks * 32 + quad * 8);
            bk[ks] = ldfrag_f32(Wk + (w * 16 + lq) * DDIM + ks * 32 + quad * 8);
        }
        #pragma unroll
        for (int m = 0; m < 8; m++) {
            f32x4 accq = {0, 0, 0, 0}, acck = {0, 0, 0, 0};
            #pragma unroll
            for (int ks = 0; ks < 4; ks++) {
                bf16x8 a = ldfrag(bufA + (m * 16 + lq) * PIT + ks * 32 + quad * 8);
                accq = mfma16(a, bq[ks], accq);
                acck = mfma16(a, bk[ks], acck);
            }
            #pragma unroll
            for (int r = 0; r < 4; r++) {
                int t = m * 16 + quad * 4 + r;
                bufB[t * PIT + w * 16 + lq] = f2b(accq[r]);
                bufC[t * PIT + w * 16 + lq] = f2b(acck[r]);
            }
        }
        // Vt = Wv @ hs^T : waves over M (o-rows). A = Wv rows, B = hs rows.
        bf16x8 av[4];
        #pragma unroll
        for (int ks = 0; ks < 4; ks++)
            av[ks] = ldfrag_f32(Wv + (w * 16 + lq) * DDIM + ks * 32 + quad * 8);
        #pragma unroll
        for (int n = 0; n < 8; n++) {
            f32x4 acc = {0, 0, 0, 0};
            #pragma unroll
            for (int ks = 0; ks < 4; ks++) {
                bf16x8 bh = ldfrag(bufA + (n * 16 + lq) * PIT + ks * 32 + quad * 8);
                acc = mfma16(av[ks], bh, acc);
            }
            #pragma unroll
            for (int r = 0; r < 4; r++) {
                int o = w * 16 + quad * 4 + r;
                bufD[o * PIT + n * 16 + lq] = f2b(acc[r]);
            }
        }
    }
    __syncthreads();

    // ---------------- P2: attention, head by head ----------------
    const float SCALE = 0.08838834764831845f;  // 128^-0.5 (full embed dim, per reference)
    #pragma unroll 1
    for (int h = 0; h < 4; h++) {
        // S = Q_h @ K_h^T ; wave w owns rows [w*16, w*16+16)
        bf16x8 aq = ldfrag(bufB + (w * 16 + lq) * PIT + h * 32 + quad * 8);
        float p[8][4];
        #pragma unroll
        for (int n = 0; n < 8; n++) {
            bf16x8 bk = ldfrag(bufC + (n * 16 + lq) * PIT + h * 32 + quad * 8);
            f32x4 s4 = {0, 0, 0, 0};
            s4 = mfma16(aq, bk, s4);
            #pragma unroll
            for (int r = 0; r < 4; r++) p[n][r] = s4[r];
        }
        // causal mask + softmax; masked entries never go through expf
        #pragma unroll
        for (int r = 0; r < 4; r++) {
            int t = w * 16 + quad * 4 + r;
            float mx = -3.0e38f;
            #pragma unroll
            for (int n = 0; n < 8; n++) {
                int sc = n * 16 + lq;
                float val = p[n][r] * SCALE;
                p[n][r] = val;
                mx = (sc <= t) ? fmaxf(mx, val) : mx;
            }
            mx = fmaxf(mx, __shfl_xor(mx, 1));
            mx = fmaxf(mx, __shfl_xor(mx, 2));
            mx = fmaxf(mx, __shfl_xor(mx, 4));
            mx = fmaxf(mx, __shfl_xor(mx, 8));
            float sum = 0.f;
            #pragma unroll
            for (int n = 0; n < 8; n++) {
                int sc = n * 16 + lq;
                float e = (sc <= t) ? __expf(p[n][r] - mx) : 0.f;
                p[n][r] = e; sum += e;
            }
            sum += __shfl_xor(sum, 1);
            sum += __shfl_xor(sum, 2);
            sum += __shfl_xor(sum, 4);
            sum += __shfl_xor(sum, 8);
            float inv = 1.f / sum;    // sum >= 1 (max lane contributes exp(0)=1)
            #pragma unroll
            for (int n = 0; n < 8; n++)
                bufA[t * PIT + n * 16 + lq] = f2b(p[n][r] * inv);
        }
        __syncthreads();
        // attn_h = P @ V_h  (B-frags from transposed V -> contiguous)
        f32x4 o0 = {0, 0, 0, 0}, o1 = {0, 0, 0, 0};
        #pragma unroll
        for (int ks = 0; ks < 4; ks++) {
            bf16x8 ap  = ldfrag(bufA + (w * 16 + lq) * PIT + ks * 32 + quad * 8);
            bf16x8 bv0 = ldfrag(bufD + (h * 32 + lq) * PIT + ks * 32 + quad * 8);
            bf16x8 bv1 = ldfrag(bufD + (h * 32 + 16 + lq) * PIT + ks * 32 + quad * 8);
            o0 = mfma16(ap, bv0, o0);
            o1 = mfma16(ap, bv1, o1);
        }
        __syncthreads();
        // overwrite Q_h columns with attn_h (wave-local rows; Q_h fully consumed)
        #pragma unroll
        for (int r = 0; r < 4; r++) {
            int t = w * 16 + quad * 4 + r;
            bufB[t * PIT + h * 32 + lq]      = f2b(o0[r]);
            bufB[t * PIT + h * 32 + 16 + lq] = f2b(o1[r]);
        }
    }
    __syncthreads();

    // ---------------- P3: x1 = x + attn @ Wo^T + bo -> regs (f32) + bufC (bf16) ----------------
    float x1res[8][4];   // f32 residual kept in registers for P6
    const int dcol = w * 16 + lq;
    {
        bf16x8 bw[4];
        #pragma unroll
        for (int ks = 0; ks < 4; ks++)
            bw[ks] = ldfrag_f32(Wo + (w * 16 + lq) * DDIM + ks * 32 + quad * 8);
        const float bov = bo[dcol];
        #pragma unroll
        for (int m = 0; m < 8; m++) {
            f32x4 acc = {0, 0, 0, 0};
            #pragma unroll
            for (int ks = 0; ks < 4; ks++) {
                bf16x8 a = ldfrag(bufB + (m * 16 + lq) * PIT + ks * 32 + quad * 8);
                acc = mfma16(a, bw[ks], acc);
            }
            #pragma unroll
            for (int r = 0; r < 4; r++) {
                int t = m * 16 + quad * 4 + r;
                float xv = xb[t * DDIM + dcol];
                float x1 = acc[r] + xv + bov;
                x1res[m][r] = x1;
                bufC[t * PIT + dcol] = f2b(x1);
            }
        }
    }
    __syncthreads();

    // ---------------- P4: LN2(x1) -> bufD (bf16) ----------------
    {
        const int row = tid >> 2, part = tid & 3;
        const u16* src = bufC + row * PIT + part * 32;
        float v[32];
        float s = 0.f, s2 = 0.f;
        #pragma unroll
        for (int i = 0; i < 4; i++) {
            uint4 u = *reinterpret_cast<const uint4*>(src + i * 8);
            u32 arr[4] = {u.x, u.y, u.z, u.w};
            #pragma unroll
            for (int j = 0; j < 4; j++) {
                float f0 = __uint_as_float((arr[j] & 0xffffu) << 16);
                float f1 = __uint_as_float(arr[j] & 0xffff0000u);
                v[i * 8 + 2 * j] = f0; v[i * 8 + 2 * j + 1] = f1;
                s += f0 + f1; s2 += f0 * f0 + f1 * f1;
            }
        }
        s  += __shfl_xor(s, 1);  s2 += __shfl_xor(s2, 1);
        s  += __shfl_xor(s, 2);  s2 += __shfl_xor(s2, 2);
        float mean = s * (1.f / 128.f);
        float var  = fmaxf(s2 * (1.f / 128.f) - mean * mean, 0.f);
        float rstd = rsqrtf(var + 1e-5f);
        u16* dst = bufD + row * PIT + part * 32;
        #pragma unroll
        for (int i = 0; i < 4; i++) {
            u32 o4[4];
            #pragma unroll
            for (int j = 0; j < 4; j++) {
                int c = part * 32 + i * 8 + 2 * j;
                float r0 = (v[i * 8 + 2 * j]     - mean) * rstd * ln2g[c]     + ln2b[c];
                float r1 = (v[i * 8 + 2 * j + 1] - mean) * rstd * ln2g[c + 1] + ln2b[c + 1];
                o4[j] = (u32)f2b(r0) | ((u32)f2b(r1) << 16);
            }
            uint4 pk; pk.x = o4[0]; pk.y = o4[1]; pk.z = o4[2]; pk.w = o4[3];
            *reinterpret_cast<uint4*>(dst + i * 8) = pk;
        }
    }
    __syncthreads();

    // ---------------- P5: FF with register accumulation over f-chunks ----------------
    f32x4 oacc[8];
    #pragma unroll
    for (int m = 0; m < 8; m++) oacc[m] = f32x4{0, 0, 0, 0};

    #pragma unroll 1
    for (int fc = 0; fc < 4; fc++) {
        const int fbase = fc * 128;
        // G = relu(h2 @ W1c^T + b1) -> bufA
        bf16x8 wf1[4];
        #pragma unroll
        for (int ks = 0; ks < 4; ks++)
            wf1[ks] = ldfrag_f32(W1 + (fbase + w * 16 + lq) * DDIM + ks * 32 + quad * 8);
        const float b1v = b1[fbase + w * 16 + lq];
        #pragma unroll
        for (int m = 0; m < 8; m++) {
            f32x4 acc = {0, 0, 0, 0};
            #pragma unroll
            for (int ks = 0; ks < 4; ks++) {
                bf16x8 a = ldfrag(bufD + (m * 16 + lq) * PIT + ks * 32 + quad * 8);
                acc = mfma16(a, wf1[ks], acc);
            }
            #pragma unroll
            for (int r = 0; r < 4; r++) {
                int t = m * 16 + quad * 4 + r;
                float g = acc[r] + b1v;
                g = g > 0.f ? g : 0.f;
                bufA[t * PIT + w * 16 + lq] = f2b(g);
            }
        }
        __syncthreads();
        // oacc += G @ W2c^T
        bf16x8 wf2[4];
        #pragma unroll
        for (int ks = 0; ks < 4; ks++)
            wf2[ks] = ldfrag_f32(W2 + (w * 16 + lq) * FFD + fbase + ks * 32 + quad * 8);
        #pragma unroll
        for (int m = 0; m < 8; m++) {
            #pragma unroll
            for (int ks = 0; ks < 4; ks++) {
                bf16x8 a = ldfrag(bufA + (m * 16 + lq) * PIT + ks * 32 + quad * 8);
                oacc[m] = mfma16(a, wf2[ks], oacc[m]);
            }
        }
        __syncthreads();
    }

    // ---------------- P6: out = x1(f32 regs) + ff + b2 -> FLOAT32 ----------------
    {
        const float b2v = b2[dcol];
        float* ob = out + (size_t)b * (TT * DDIM);
        #pragma unroll
        for (int m = 0; m < 8; m++) {
            #pragma unroll
            for (int r = 0; r < 4; r++) {
                int t = m * 16 + quad * 4 + r;
                ob[t * DDIM + dcol] = oacc[m][r] + x1res[m][r] + b2v;
            }
        }
    }
}

extern "C" void kernel_launch(void* const* d_in, const int* in_sizes, int n_in,
                              void* d_out, int out_size, void* d_ws, size_t ws_size,
                              hipStream_t stream) {
    const float* x    = (const float*)d_in[0];
    const float* ln1g = (const float*)d_in[1];
    const float* ln1b = (const float*)d_in[2];
    const float* Wq   = (const float*)d_in[3];
    const float* Wk   = (const float*)d_in[4];
    const float* Wv   = (const float*)d_in[5];
    const float* Wo   = (const float*)d_in[6];
    const float* bo   = (const float*)d_in[7];
    const float* ln2g = (const float*)d_in[8];
    const float* ln2b = (const float*)d_in[9];
    const float* W1   = (const float*)d_in[10];
    const float* b1   = (const float*)d_in[11];
    const float* W2   = (const float*)d_in[12];
    const float* b2   = (const float*)d_in[13];
    float* out = (float*)d_out;

    const int nblocks = in_sizes[0] / (TT * DDIM);   // B = 1024
    tblock_kernel<<<dim3(nblocks), dim3(512), 0, stream>>>(
        x, ln1g, ln1b, Wq, Wk, Wv, Wo, bo, ln2g, ln2b, W1, b1, W2, b2, out);
}